// Round 6
// baseline (266.881 us; speedup 1.0000x reference)
//
#include <hip/hip_runtime.h>
#include <hip/hip_bf16.h>
#include <math.h>

#define BB 2
#define SS 2048
#define DD 1024
#define HH 16
#define HDD 64

typedef float f32x4 __attribute__((ext_vector_type(4)));
typedef short s16x8 __attribute__((ext_vector_type(8)));
typedef unsigned short u16x8 __attribute__((ext_vector_type(8)));

__device__ inline unsigned short f2bf(float x) {
  unsigned u = __float_as_uint(x);
  unsigned r = u + 0x7fff + ((u >> 16) & 1);  // RNE
  return (unsigned short)(r >> 16);
}
__device__ inline float bf2f(unsigned short h) {
  return __uint_as_float(((unsigned)h) << 16);
}

// ---------------- pre-pass: cast fp32 -> bf16 (A operand, hi only) ---------
__global__ __launch_bounds__(256) void cast_bf16_kernel(const float* __restrict__ X,
                                                        unsigned short* __restrict__ Xb,
                                                        int n4) {
  int i = blockIdx.x * 256 + threadIdx.x;
  if (i >= n4) return;
  float4 v = ((const float4*)X)[i];
  ushort4 h;
  h.x = f2bf(v.x); h.y = f2bf(v.y); h.z = f2bf(v.z); h.w = f2bf(v.w);
  ((ushort4*)Xb)[i] = h;
}

// -------- pre-pass: split + transpose W[K][N] -> WT_h/WT_l [N][K] ----------
__global__ __launch_bounds__(256) void split_transpose_kernel(
    const float* __restrict__ W, unsigned short* __restrict__ WTh,
    unsigned short* __restrict__ WTl, int K, int N) {
  __shared__ float tile[64][65];
  const int k0 = blockIdx.y * 64, n0 = blockIdx.x * 64;
  const int t = threadIdx.x;
  const int c = t & 63, rq = t >> 6;
#pragma unroll
  for (int u = 0; u < 16; ++u) {
    int r = u * 4 + rq;
    tile[r][c] = W[(size_t)(k0 + r) * N + n0 + c];
  }
  __syncthreads();
#pragma unroll
  for (int u = 0; u < 16; ++u) {
    int nl = u * 4 + rq;
    float v = tile[c][nl];  // = W[k0+c][n0+nl]
    unsigned short h = f2bf(v);
    unsigned short l = f2bf(v - bf2f(h));
    size_t o = (size_t)(n0 + nl) * K + k0 + c;
    WTh[o] = h;
    WTl[o] = l;
  }
}

#define GLDS16(g, l)                                                        \
  __builtin_amdgcn_global_load_lds(                                         \
      (const __attribute__((address_space(1))) unsigned int*)(const void*)(g), \
      (__attribute__((address_space(3))) unsigned int*)(l), 16, 0, 0)

// =================== 2-term GEMM core (A bf16, B hi/lo) ====================
// Staging maps: linear LDS dest, inverse-swizzled global source (rule #21).
#define GEMM2T_PRE(Ab, BTh, BTl, Kdim)                                      \
  const int t = threadIdx.x;                                                \
  const int bm = blockIdx.y * 128;                                          \
  const int bn = blockIdx.x * 128;                                          \
  const int w = t >> 6, lane = t & 63;                                      \
  const int wrow = (w >> 1) * 64, wcol = (w & 1) * 64;                      \
  const int l15 = lane & 15, l4 = lane >> 4, l7 = lane & 7;                 \
  int ldsoff[4];                                                            \
  const unsigned short* pA[4];                                              \
  const unsigned short* pBh[4];                                             \
  const unsigned short* pBl[4];                                             \
  _Pragma("unroll")                                                         \
  for (int cc = 0; cc < 4; ++cc) {                                          \
    int tp = t + cc * 256;                                                  \
    int srow = tp >> 3;                                                     \
    int gq = (tp & 7) ^ (srow & 7);                                         \
    ldsoff[cc] = tp * 8;                                                    \
    pA[cc]  = (Ab)  + (size_t)(bm + srow) * (Kdim) + gq * 8;                \
    pBh[cc] = (BTh) + (size_t)(bn + srow) * (Kdim) + gq * 8;                \
    pBl[cc] = (BTl) + (size_t)(bn + srow) * (Kdim) + gq * 8;                \
  }                                                                         \
  f32x4 acc[4][4];                                                          \
  const f32x4 z = {0.f, 0.f, 0.f, 0.f};                                     \
  _Pragma("unroll")                                                         \
  for (int m = 0; m < 4; ++m)                                               \
    _Pragma("unroll")                                                       \
    for (int n = 0; n < 4; ++n) acc[m][n] = z;                              \
  for (int k0 = 0; k0 < (Kdim); k0 += 64) {                                 \
    __syncthreads();                                                        \
    _Pragma("unroll")                                                       \
    for (int cc = 0; cc < 4; ++cc) {                                        \
      GLDS16(pA[cc] + k0, &As_b[ldsoff[cc]]);                               \
      GLDS16(pBh[cc] + k0, &Bs_h[ldsoff[cc]]);                              \
      GLDS16(pBl[cc] + k0, &Bs_l[ldsoff[cc]]);                              \
    }                                                                       \
    __syncthreads();                                                        \
    _Pragma("unroll")                                                       \
    for (int ks = 0; ks < 2; ++ks) {                                        \
      const int sw = ((ks * 4 + l4) ^ l7) * 8;                              \
      s16x8 a[4], bh[4], bl[4];                                             \
      _Pragma("unroll")                                                     \
      for (int m = 0; m < 4; ++m)                                           \
        a[m] = *(const s16x8*)&As_b[(wrow + m * 16 + l15) * 64 + sw];       \
      _Pragma("unroll")                                                     \
      for (int n = 0; n < 4; ++n) {                                         \
        int idx = (wcol + n * 16 + l15) * 64 + sw;                          \
        bh[n] = *(const s16x8*)&Bs_h[idx];                                  \
        bl[n] = *(const s16x8*)&Bs_l[idx];                                  \
      }                                                                     \
      _Pragma("unroll")                                                     \
      for (int m = 0; m < 4; ++m)                                           \
        _Pragma("unroll")                                                   \
        for (int n = 0; n < 4; ++n) {                                       \
          acc[m][n] = __builtin_amdgcn_mfma_f32_16x16x32_bf16(a[m], bh[n], acc[m][n], 0, 0, 0); \
          acc[m][n] = __builtin_amdgcn_mfma_f32_16x16x32_bf16(a[m], bl[n], acc[m][n], 0, 0, 0); \
        }                                                                   \
    }                                                                       \
  }

// ---- GEMM1: fused QKV proj + RoPE + head-split + V-transpose epilogue -----
__global__ __launch_bounds__(256) void gemm_qkv_rope_kernel(
    const unsigned short* __restrict__ Ab,
    const unsigned short* __restrict__ BTh, const unsigned short* __restrict__ BTl,
    const float* __restrict__ sin_q, const float* __restrict__ cos_q,
    const float* __restrict__ sin_k, const float* __restrict__ cos_k,
    unsigned short* __restrict__ Qhi, unsigned short* __restrict__ Qlo,
    unsigned short* __restrict__ Khi, unsigned short* __restrict__ Vt) {
  __shared__ __align__(16) unsigned short As_b[128 * 64];
  __shared__ __align__(16) unsigned short Bs_h[128 * 64];
  __shared__ __align__(16) unsigned short Bs_l[128 * 64];
  GEMM2T_PRE(Ab, BTh, BTl, DD)

  const int region = bn >> 10;
  const int hloc = ((bn & 1023) + wcol) >> 6;
  const float QSC = 0.125f * 1.44269504088896340736f;  // 1/sqrt(HD) * log2(e)

  if (region == 0) {  // Q: rope, scale, split hi/lo
#pragma unroll
    for (int m = 0; m < 4; ++m) {
      const int row0 = bm + wrow + m * 16 + l4 * 4;
#pragma unroll
      for (int r = 0; r < 4; ++r) {
        const int row = row0 + r, b = row >> 11, s = row & 2047;
        const size_t ob = ((size_t)(b * HH + hloc) * SS + s) * HDD;
        const float* cq = cos_q + s * HDD;
        const float* sq = sin_q + s * HDD;
#pragma unroll
        for (int np = 0; np < 2; ++np) {
          const int d1 = np * 16 + l15;
          float x1 = acc[m][np][r], x2 = acc[m][np + 2][r];
          float q1 = (x1 * cq[d1] - x2 * sq[d1]) * QSC;
          float q2 = (x2 * cq[d1 + 32] + x1 * sq[d1 + 32]) * QSC;
          unsigned short h1 = f2bf(q1), h2 = f2bf(q2);
          Qhi[ob + d1] = h1;      Qlo[ob + d1] = f2bf(q1 - bf2f(h1));
          Qhi[ob + d1 + 32] = h2; Qlo[ob + d1 + 32] = f2bf(q2 - bf2f(h2));
        }
      }
    }
  } else if (region == 1) {  // K: rope, single bf16
#pragma unroll
    for (int m = 0; m < 4; ++m) {
      const int row0 = bm + wrow + m * 16 + l4 * 4;
#pragma unroll
      for (int r = 0; r < 4; ++r) {
        const int row = row0 + r, b = row >> 11, s = row & 2047;
        const size_t ob = ((size_t)(b * HH + hloc) * SS + s) * HDD;
        const float* ck = cos_k + s * HDD;
        const float* sk = sin_k + s * HDD;
#pragma unroll
        for (int np = 0; np < 2; ++np) {
          const int d1 = np * 16 + l15;
          float x1 = acc[m][np][r], x2 = acc[m][np + 2][r];
          Khi[ob + d1]      = f2bf(x1 * ck[d1] - x2 * sk[d1]);
          Khi[ob + d1 + 32] = f2bf(x2 * ck[d1 + 32] + x1 * sk[d1 + 32]);
        }
      }
    }
  } else {  // V: transpose to [B,H,HD,S]
#pragma unroll
    for (int m = 0; m < 4; ++m) {
      const int row0 = bm + wrow + m * 16 + l4 * 4;
      const int b = row0 >> 11, s0 = row0 & 2047;
#pragma unroll
      for (int n = 0; n < 4; ++n) {
        const int d = n * 16 + l15;
        ushort4 v4;
        v4.x = f2bf(acc[m][n][0]);
        v4.y = f2bf(acc[m][n][1]);
        v4.z = f2bf(acc[m][n][2]);
        v4.w = f2bf(acc[m][n][3]);
        *(ushort4*)&Vt[((size_t)(b * HH + hloc) * HDD + d) * SS + s0] = v4;
      }
    }
  }
}

// ---- GEMM2: output projection, fp32 C ----
__global__ __launch_bounds__(256) void gemm_out_kernel(
    const unsigned short* __restrict__ Ab,
    const unsigned short* __restrict__ BTh, const unsigned short* __restrict__ BTl,
    float* __restrict__ C) {
  __shared__ __align__(16) unsigned short As_b[128 * 64];
  __shared__ __align__(16) unsigned short Bs_h[128 * 64];
  __shared__ __align__(16) unsigned short Bs_l[128 * 64];
  GEMM2T_PRE(Ab, BTh, BTl, DD)

#pragma unroll
  for (int m = 0; m < 4; ++m)
#pragma unroll
    for (int n = 0; n < 4; ++n) {
      f32x4 v = acc[m][n];
      int col = bn + wcol + n * 16 + l15;
      int row0 = bm + wrow + m * 16 + l4 * 4;
#pragma unroll
      for (int r = 0; r < 4; ++r) C[(size_t)(row0 + r) * DD + col] = v[r];
    }
}

// ------------- causal flash attention, bf16 MFMA, KB=128 tiles -------------
// Paired Q-tiles (31-p, p), 64 q-rows each; K-tiles 128 wide; single-buffer
// LDS with T14 async reg-staging (issue loads early, ds_write after barrier).
// Q hi/lo in regs (2-MFMA QK^T); exp2-domain; l via MFMA ones; defer-max.

#define ATTN_TILE128(QH, QL, OO, LS, MM, MASKED, QI)                             \
  do {                                                                           \
    f32x4 sc[8];                                                                 \
    _Pragma("unroll")                                                            \
    for (int n = 0; n < 8; ++n) sc[n] = z;                                       \
    __builtin_amdgcn_s_setprio(1);                                               \
    _Pragma("unroll")                                                            \
    for (int kc = 0; kc < 2; ++kc) {                                             \
      const int swz = ((kc * 4 + l4) ^ l7) * 8;                                  \
      _Pragma("unroll")                                                          \
      for (int n = 0; n < 8; ++n) {                                              \
        s16x8 kh = *(const s16x8*)&Ks[(n * 16 + l15) * 64 + swz];                \
        sc[n] = __builtin_amdgcn_mfma_f32_16x16x32_bf16(QH[kc], kh, sc[n], 0, 0, 0); \
        sc[n] = __builtin_amdgcn_mfma_f32_16x16x32_bf16(QL[kc], kh, sc[n], 0, 0, 0); \
      }                                                                          \
    }                                                                            \
    __builtin_amdgcn_s_setprio(0);                                               \
    if (MASKED) {                                                                \
      _Pragma("unroll")                                                          \
      for (int n = 0; n < 8; ++n) {                                              \
        const int colg = ktb + n * 16 + l15;                                     \
        _Pragma("unroll")                                                        \
        for (int r = 0; r < 4; ++r)                                              \
          if (colg > (QI) * 64 + rowl + r) sc[n][r] = -INFINITY;                 \
      }                                                                          \
    }                                                                            \
    float pm[4];                                                                 \
    _Pragma("unroll")                                                            \
    for (int r = 0; r < 4; ++r) {                                                \
      float tm = fmaxf(fmaxf(fmaxf(sc[0][r], sc[1][r]), fmaxf(sc[2][r], sc[3][r])), \
                       fmaxf(fmaxf(sc[4][r], sc[5][r]), fmaxf(sc[6][r], sc[7][r]))); \
      tm = fmaxf(tm, __shfl_xor(tm, 1));                                         \
      tm = fmaxf(tm, __shfl_xor(tm, 2));                                         \
      tm = fmaxf(tm, __shfl_xor(tm, 4));                                         \
      tm = fmaxf(tm, __shfl_xor(tm, 8));                                         \
      pm[r] = tm;                                                                 \
    }                                                                            \
    float growth = fmaxf(fmaxf(pm[0] - MM[0], pm[1] - MM[1]),                    \
                         fmaxf(pm[2] - MM[2], pm[3] - MM[3]));                   \
    if (!__all(growth <= 8.f)) {                                                 \
      _Pragma("unroll")                                                          \
      for (int r = 0; r < 4; ++r) {                                              \
        float mn = fmaxf(MM[r], pm[r]);                                          \
        float corr = __builtin_amdgcn_exp2f(MM[r] - mn);                         \
        MM[r] = mn;                                                              \
        OO[0][r] *= corr; OO[1][r] *= corr; OO[2][r] *= corr; OO[3][r] *= corr;  \
        LS[r] *= corr;                                                           \
      }                                                                          \
    }                                                                            \
    _Pragma("unroll")                                                            \
    for (int r = 0; r < 4; ++r) {                                                \
      const int pr = (rowl + r) * 136;                                           \
      _Pragma("unroll")                                                          \
      for (int n = 0; n < 8; ++n)                                                \
        Ps[pr + n * 16 + l15] = f2bf(__builtin_amdgcn_exp2f(sc[n][r] - MM[r]));  \
    }                                                                            \
    const int prow = (w * 16 + l15) * 136;                                       \
    __builtin_amdgcn_s_setprio(1);                                               \
    _Pragma("unroll")                                                            \
    for (int c = 0; c < 4; ++c) {                                                \
      s16x8 pa = *(const s16x8*)&Ps[prow + c * 32 + 8 * l4];                     \
      const int q = c * 4 + l4;                                                  \
      const int rq = (q & 8) | ((q ^ l7) & 7);                                   \
      _Pragma("unroll")                                                          \
      for (int n = 0; n < 4; ++n) {                                              \
        s16x8 vb = *(const s16x8*)&Vs[(n * 16 + l15) * 128 + rq * 8];            \
        OO[n] = __builtin_amdgcn_mfma_f32_16x16x32_bf16(pa, vb, OO[n], 0, 0, 0); \
      }                                                                          \
      LS = __builtin_amdgcn_mfma_f32_16x16x32_bf16(pa, ones, LS, 0, 0, 0);       \
    }                                                                            \
    __builtin_amdgcn_s_setprio(0);                                               \
  } while (0)

#define ATTN_EPI(OO, LS, QI)                                                     \
  do {                                                                           \
    _Pragma("unroll")                                                            \
    for (int r = 0; r < 4; ++r) {                                                \
      const float inv = 1.f / LS[r];                                             \
      const int orow = (QI) * 64 + rowl + r;                                     \
      const size_t ob = ((size_t)b * SS + orow) * DD + h * HDD + l15;            \
      _Pragma("unroll")                                                          \
      for (int n = 0; n < 4; ++n)                                                \
        Ohi[ob + n * 16] = f2bf(OO[n][r] * inv);                                 \
    }                                                                            \
  } while (0)

__global__ __launch_bounds__(256) void attn_mfma_kernel(
    const unsigned short* __restrict__ Qhi, const unsigned short* __restrict__ Qlo,
    const unsigned short* __restrict__ Khi_g, const unsigned short* __restrict__ Vt_g,
    unsigned short* __restrict__ Ohi) {
  __shared__ __align__(16) unsigned short Ks[128 * 64];   // [kv][d]
  __shared__ __align__(16) unsigned short Vs[64 * 128];   // [d][kv]
  __shared__ __align__(16) unsigned short Ps[64 * 136];   // [q][kv]

  const int t = threadIdx.x;
  const int lane = t & 63;
  const int w = t >> 6;
  const int p = blockIdx.x;                 // 0..15
  const int qiA = 31 - p, qiB = p;          // paired 64-row Q-tiles
  const int bh = blockIdx.y;
  const int b = bh >> 4, h = bh & 15;
  const int l15 = lane & 15, l4 = lane >> 4, l7 = lane & 7;
  const int rowl = w * 16 + l4 * 4;

  // Q fragments for both tiles (pre-scaled by 0.125*log2e in gemm1 epilogue)
  s16x8 qhA[2], qlA[2], qhB[2], qlB[2];
  {
    const int rowA = qiA * 64 + w * 16 + l15;
    const unsigned short* qb = Qhi + ((size_t)bh * SS + rowA) * HDD + 8 * l4;
    const unsigned short* qc = Qlo + ((size_t)bh * SS + rowA) * HDD + 8 * l4;
    qhA[0] = *(const s16x8*)(qb);
    qhA[1] = *(const s16x8*)(qb + 32);
    qlA[0] = *(const s16x8*)(qc);
    qlA[1] = *(const s16x8*)(qc + 32);
    const int rowB = qiB * 64 + w * 16 + l15;
    const unsigned short* qd = Qhi + ((size_t)bh * SS + rowB) * HDD + 8 * l4;
    const unsigned short* qe = Qlo + ((size_t)bh * SS + rowB) * HDD + 8 * l4;
    qhB[0] = *(const s16x8*)(qd);
    qhB[1] = *(const s16x8*)(qd + 32);
    qlB[0] = *(const s16x8*)(qe);
    qlB[1] = *(const s16x8*)(qe + 32);
  }

  // staging maps (reg-staged; LDS linear, read-side XOR swizzle, src inverse)
  int ldsk[4], ldsv[4];
  size_t koff[4], voff[4];
#pragma unroll
  for (int cc = 0; cc < 4; ++cc) {
    const int G = t + cc * 256;          // 0..1023 chunks of 8 ushorts
    const int krow = G >> 3, kg = G & 7;
    const int kgs = kg ^ (krow & 7);
    ldsk[cc] = G * 8;
    koff[cc] = ((size_t)bh * SS + krow) * HDD + kgs * 8;
    const int vrow = G >> 4, vg = G & 15;
    const int vgs = (vg & 8) | ((vg ^ vrow) & 7);
    ldsv[cc] = G * 8;
    voff[cc] = ((size_t)bh * HDD + vrow) * SS + vgs * 8;
  }

  const f32x4 z = {0.f, 0.f, 0.f, 0.f};
  f32x4 oA[4], oB[4], lsA = z, lsB = z;
#pragma unroll
  for (int n = 0; n < 4; ++n) { oA[n] = z; oB[n] = z; }
  float mA[4], mB[4];
#pragma unroll
  for (int r = 0; r < 4; ++r) { mA[r] = -INFINITY; mB[r] = -INFINITY; }

  const short one_bf = (short)0x3F80;
  const s16x8 ones = {one_bf, one_bf, one_bf, one_bf, one_bf, one_bf, one_bf, one_bf};

  const int ktA_max = qiA >> 1;
  const int ktB_max = qiB >> 1;

  // prologue: stage tile 0
  u16x8 kreg[4], vreg[4];
#pragma unroll
  for (int cc = 0; cc < 4; ++cc) {
    kreg[cc] = *(const u16x8*)(Khi_g + koff[cc]);
    vreg[cc] = *(const u16x8*)(Vt_g + voff[cc]);
  }
#pragma unroll
  for (int cc = 0; cc < 4; ++cc) {
    *(u16x8*)&Ks[ldsk[cc]] = kreg[cc];
    *(u16x8*)&Vs[ldsv[cc]] = vreg[cc];
  }
  __syncthreads();

  for (int kt = 0; kt <= ktA_max; ++kt) {
    const int ktb = kt << 7;
    const bool pf = kt < ktA_max;
    if (pf) {  // T14: issue next tile's loads into regs before compute
      const size_t ka = (size_t)(kt + 1) * 128 * HDD;
      const size_t va = (size_t)(kt + 1) * 128;
#pragma unroll
      for (int cc = 0; cc < 4; ++cc) {
        kreg[cc] = *(const u16x8*)(Khi_g + ka + koff[cc]);
        vreg[cc] = *(const u16x8*)(Vt_g + va + voff[cc]);
      }
    }
    ATTN_TILE128(qhA, qlA, oA, lsA, mA, kt == ktA_max, qiA);
    if (kt <= ktB_max) ATTN_TILE128(qhB, qlB, oB, lsB, mB, kt == ktB_max, qiB);
    if (pf) {
      __syncthreads();  // all waves done reading Ks/Vs
#pragma unroll
      for (int cc = 0; cc < 4; ++cc) {  // vmcnt drained by compiler here
        *(u16x8*)&Ks[ldsk[cc]] = kreg[cc];
        *(u16x8*)&Vs[ldsv[cc]] = vreg[cc];
      }
      __syncthreads();  // publish
    }
  }

  ATTN_EPI(oA, lsA, qiA);
  ATTN_EPI(oB, lsB, qiB);
}

extern "C" void kernel_launch(void* const* d_in, const int* in_sizes, int n_in,
                              void* d_out, int out_size, void* d_ws, size_t ws_size,
                              hipStream_t stream) {
  const float* query = (const float*)d_in[0];
  const float* sin_q = (const float*)d_in[1];
  const float* cos_q = (const float*)d_in[2];
  const float* sin_k = (const float*)d_in[3];
  const float* cos_k = (const float*)d_in[4];
  const float* w_in  = (const float*)d_in[5];
  const float* w_out = (const float*)d_in[6];
  float* out = (float*)d_out;

  const int M = BB * SS;  // 4096
  const size_t MD = (size_t)M * DD;

  unsigned char* ws = (unsigned char*)d_ws;
  size_t off = 0;
  unsigned short* Qb  = (unsigned short*)(ws + off); off += MD * 2;
  unsigned short* B1h = (unsigned short*)(ws + off); off += (size_t)DD * 3 * DD * 2;
  unsigned short* B1l = (unsigned short*)(ws + off); off += (size_t)DD * 3 * DD * 2;
  unsigned short* B2h = (unsigned short*)(ws + off); off += (size_t)DD * DD * 2;
  unsigned short* B2l = (unsigned short*)(ws + off); off += (size_t)DD * DD * 2;
  unsigned short* Qhi = (unsigned short*)(ws + off); off += MD * 2;
  unsigned short* Qlo = (unsigned short*)(ws + off); off += MD * 2;
  unsigned short* Khi = (unsigned short*)(ws + off); off += MD * 2;
  unsigned short* Vt  = (unsigned short*)(ws + off); off += MD * 2;
  unsigned short* Ohi = (unsigned short*)(ws + off); off += MD * 2;

  {  // pre-pass: A cast + weight splits
    int n4 = (int)(MD / 4);
    cast_bf16_kernel<<<(n4 + 255) / 256, 256, 0, stream>>>(query, Qb, n4);
    split_transpose_kernel<<<dim3(3 * DD / 64, DD / 64), 256, 0, stream>>>(w_in, B1h, B1l, DD, 3 * DD);
    split_transpose_kernel<<<dim3(DD / 64, DD / 64), 256, 0, stream>>>(w_out, B2h, B2l, DD, DD);
  }
  {  // 1) fused QKV projection + RoPE + head-split + V-transpose
    dim3 grid((3 * DD) / 128, M / 128);
    gemm_qkv_rope_kernel<<<grid, 256, 0, stream>>>(
        Qb, B1h, B1l, sin_q, cos_q, sin_k, cos_k, Qhi, Qlo, Khi, Vt);
  }
  {  // 2) causal attention (MFMA, KB=128, T14 async staging)
    dim3 grid(SS / 128, BB * HH);
    attn_mfma_kernel<<<grid, 256, 0, stream>>>(Qhi, Qlo, Khi, Vt, Ohi);
  }
  {  // 3) output projection
    dim3 grid(DD / 128, M / 128);
    gemm_out_kernel<<<grid, 256, 0, stream>>>(Ohi, B2h, B2l, out);
  }
}

// Round 7
// 258.770 us; speedup vs baseline: 1.0313x; 1.0313x over previous
//
#include <hip/hip_runtime.h>
#include <hip/hip_bf16.h>
#include <math.h>

#define BB 2
#define SS 2048
#define DD 1024
#define HH 16
#define HDD 64

typedef float f32x4 __attribute__((ext_vector_type(4)));
typedef short s16x8 __attribute__((ext_vector_type(8)));
typedef unsigned short u16x8 __attribute__((ext_vector_type(8)));

__device__ inline unsigned short f2bf(float x) {
  unsigned u = __float_as_uint(x);
  unsigned r = u + 0x7fff + ((u >> 16) & 1);  // RNE
  return (unsigned short)(r >> 16);
}
__device__ inline float bf2f(unsigned short h) {
  return __uint_as_float(((unsigned)h) << 16);
}

// ---------------- pre-pass: cast fp32 -> bf16 (A operand, hi only) ---------
__global__ __launch_bounds__(256) void cast_bf16_kernel(const float* __restrict__ X,
                                                        unsigned short* __restrict__ Xb,
                                                        int n4) {
  int i = blockIdx.x * 256 + threadIdx.x;
  if (i >= n4) return;
  float4 v = ((const float4*)X)[i];
  ushort4 h;
  h.x = f2bf(v.x); h.y = f2bf(v.y); h.z = f2bf(v.z); h.w = f2bf(v.w);
  ((ushort4*)Xb)[i] = h;
}

// -------- pre-pass: split + transpose W[K][N] -> WT_h/WT_l [N][K] ----------
__global__ __launch_bounds__(256) void split_transpose_kernel(
    const float* __restrict__ W, unsigned short* __restrict__ WTh,
    unsigned short* __restrict__ WTl, int K, int N) {
  __shared__ float tile[64][65];
  const int k0 = blockIdx.y * 64, n0 = blockIdx.x * 64;
  const int t = threadIdx.x;
  const int c = t & 63, rq = t >> 6;
#pragma unroll
  for (int u = 0; u < 16; ++u) {
    int r = u * 4 + rq;
    tile[r][c] = W[(size_t)(k0 + r) * N + n0 + c];
  }
  __syncthreads();
#pragma unroll
  for (int u = 0; u < 16; ++u) {
    int nl = u * 4 + rq;
    float v = tile[c][nl];  // = W[k0+c][n0+nl]
    unsigned short h = f2bf(v);
    unsigned short l = f2bf(v - bf2f(h));
    size_t o = (size_t)(n0 + nl) * K + k0 + c;
    WTh[o] = h;
    WTl[o] = l;
  }
}

#define GLDS16(g, l)                                                        \
  __builtin_amdgcn_global_load_lds(                                         \
      (const __attribute__((address_space(1))) unsigned int*)(const void*)(g), \
      (__attribute__((address_space(3))) unsigned int*)(l), 16, 0, 0)

// =================== 2-term GEMM core (A bf16, B hi/lo) ====================
// Staging maps: linear LDS dest, inverse-swizzled global source (rule #21).
#define GEMM2T_PRE(Ab, BTh, BTl, Kdim)                                      \
  const int t = threadIdx.x;                                                \
  const int bm = blockIdx.y * 128;                                          \
  const int bn = blockIdx.x * 128;                                          \
  const int w = t >> 6, lane = t & 63;                                      \
  const int wrow = (w >> 1) * 64, wcol = (w & 1) * 64;                      \
  const int l15 = lane & 15, l4 = lane >> 4, l7 = lane & 7;                 \
  int ldsoff[4];                                                            \
  const unsigned short* pA[4];                                              \
  const unsigned short* pBh[4];                                             \
  const unsigned short* pBl[4];                                             \
  _Pragma("unroll")                                                         \
  for (int cc = 0; cc < 4; ++cc) {                                          \
    int tp = t + cc * 256;                                                  \
    int srow = tp >> 3;                                                     \
    int gq = (tp & 7) ^ (srow & 7);                                         \
    ldsoff[cc] = tp * 8;                                                    \
    pA[cc]  = (Ab)  + (size_t)(bm + srow) * (Kdim) + gq * 8;                \
    pBh[cc] = (BTh) + (size_t)(bn + srow) * (Kdim) + gq * 8;                \
    pBl[cc] = (BTl) + (size_t)(bn + srow) * (Kdim) + gq * 8;                \
  }                                                                         \
  f32x4 acc[4][4];                                                          \
  const f32x4 z = {0.f, 0.f, 0.f, 0.f};                                     \
  _Pragma("unroll")                                                         \
  for (int m = 0; m < 4; ++m)                                               \
    _Pragma("unroll")                                                       \
    for (int n = 0; n < 4; ++n) acc[m][n] = z;                              \
  for (int k0 = 0; k0 < (Kdim); k0 += 64) {                                 \
    __syncthreads();                                                        \
    _Pragma("unroll")                                                       \
    for (int cc = 0; cc < 4; ++cc) {                                        \
      GLDS16(pA[cc] + k0, &As_b[ldsoff[cc]]);                               \
      GLDS16(pBh[cc] + k0, &Bs_h[ldsoff[cc]]);                              \
      GLDS16(pBl[cc] + k0, &Bs_l[ldsoff[cc]]);                              \
    }                                                                       \
    __syncthreads();                                                        \
    _Pragma("unroll")                                                       \
    for (int ks = 0; ks < 2; ++ks) {                                        \
      const int sw = ((ks * 4 + l4) ^ l7) * 8;                              \
      s16x8 a[4], bh[4], bl[4];                                             \
      _Pragma("unroll")                                                     \
      for (int m = 0; m < 4; ++m)                                           \
        a[m] = *(const s16x8*)&As_b[(wrow + m * 16 + l15) * 64 + sw];       \
      _Pragma("unroll")                                                     \
      for (int n = 0; n < 4; ++n) {                                         \
        int idx = (wcol + n * 16 + l15) * 64 + sw;                          \
        bh[n] = *(const s16x8*)&Bs_h[idx];                                  \
        bl[n] = *(const s16x8*)&Bs_l[idx];                                  \
      }                                                                     \
      _Pragma("unroll")                                                     \
      for (int m = 0; m < 4; ++m)                                           \
        _Pragma("unroll")                                                   \
        for (int n = 0; n < 4; ++n) {                                       \
          acc[m][n] = __builtin_amdgcn_mfma_f32_16x16x32_bf16(a[m], bh[n], acc[m][n], 0, 0, 0); \
          acc[m][n] = __builtin_amdgcn_mfma_f32_16x16x32_bf16(a[m], bl[n], acc[m][n], 0, 0, 0); \
        }                                                                   \
    }                                                                       \
  }

// ---- GEMM1: fused QKV proj + RoPE + head-split + V-transpose epilogue -----
__global__ __launch_bounds__(256) void gemm_qkv_rope_kernel(
    const unsigned short* __restrict__ Ab,
    const unsigned short* __restrict__ BTh, const unsigned short* __restrict__ BTl,
    const float* __restrict__ sin_q, const float* __restrict__ cos_q,
    const float* __restrict__ sin_k, const float* __restrict__ cos_k,
    unsigned short* __restrict__ Qhi, unsigned short* __restrict__ Qlo,
    unsigned short* __restrict__ Khi, unsigned short* __restrict__ Vt) {
  __shared__ __align__(16) unsigned short As_b[128 * 64];
  __shared__ __align__(16) unsigned short Bs_h[128 * 64];
  __shared__ __align__(16) unsigned short Bs_l[128 * 64];
  GEMM2T_PRE(Ab, BTh, BTl, DD)

  const int region = bn >> 10;
  const int hloc = ((bn & 1023) + wcol) >> 6;
  const float QSC = 0.125f * 1.44269504088896340736f;  // 1/sqrt(HD) * log2(e)

  if (region == 0) {  // Q: rope, scale, split hi/lo
#pragma unroll
    for (int m = 0; m < 4; ++m) {
      const int row0 = bm + wrow + m * 16 + l4 * 4;
#pragma unroll
      for (int r = 0; r < 4; ++r) {
        const int row = row0 + r, b = row >> 11, s = row & 2047;
        const size_t ob = ((size_t)(b * HH + hloc) * SS + s) * HDD;
        const float* cq = cos_q + s * HDD;
        const float* sq = sin_q + s * HDD;
#pragma unroll
        for (int np = 0; np < 2; ++np) {
          const int d1 = np * 16 + l15;
          float x1 = acc[m][np][r], x2 = acc[m][np + 2][r];
          float q1 = (x1 * cq[d1] - x2 * sq[d1]) * QSC;
          float q2 = (x2 * cq[d1 + 32] + x1 * sq[d1 + 32]) * QSC;
          unsigned short h1 = f2bf(q1), h2 = f2bf(q2);
          Qhi[ob + d1] = h1;      Qlo[ob + d1] = f2bf(q1 - bf2f(h1));
          Qhi[ob + d1 + 32] = h2; Qlo[ob + d1 + 32] = f2bf(q2 - bf2f(h2));
        }
      }
    }
  } else if (region == 1) {  // K: rope, single bf16
#pragma unroll
    for (int m = 0; m < 4; ++m) {
      const int row0 = bm + wrow + m * 16 + l4 * 4;
#pragma unroll
      for (int r = 0; r < 4; ++r) {
        const int row = row0 + r, b = row >> 11, s = row & 2047;
        const size_t ob = ((size_t)(b * HH + hloc) * SS + s) * HDD;
        const float* ck = cos_k + s * HDD;
        const float* sk = sin_k + s * HDD;
#pragma unroll
        for (int np = 0; np < 2; ++np) {
          const int d1 = np * 16 + l15;
          float x1 = acc[m][np][r], x2 = acc[m][np + 2][r];
          Khi[ob + d1]      = f2bf(x1 * ck[d1] - x2 * sk[d1]);
          Khi[ob + d1 + 32] = f2bf(x2 * ck[d1 + 32] + x1 * sk[d1 + 32]);
        }
      }
    }
  } else {  // V: transpose to [B,H,HD,S]
#pragma unroll
    for (int m = 0; m < 4; ++m) {
      const int row0 = bm + wrow + m * 16 + l4 * 4;
      const int b = row0 >> 11, s0 = row0 & 2047;
#pragma unroll
      for (int n = 0; n < 4; ++n) {
        const int d = n * 16 + l15;
        ushort4 v4;
        v4.x = f2bf(acc[m][n][0]);
        v4.y = f2bf(acc[m][n][1]);
        v4.z = f2bf(acc[m][n][2]);
        v4.w = f2bf(acc[m][n][3]);
        *(ushort4*)&Vt[((size_t)(b * HH + hloc) * HDD + d) * SS + s0] = v4;
      }
    }
  }
}

// ---- GEMM2: output projection, fp32 C ----
__global__ __launch_bounds__(256) void gemm_out_kernel(
    const unsigned short* __restrict__ Ab,
    const unsigned short* __restrict__ BTh, const unsigned short* __restrict__ BTl,
    float* __restrict__ C) {
  __shared__ __align__(16) unsigned short As_b[128 * 64];
  __shared__ __align__(16) unsigned short Bs_h[128 * 64];
  __shared__ __align__(16) unsigned short Bs_l[128 * 64];
  GEMM2T_PRE(Ab, BTh, BTl, DD)

#pragma unroll
  for (int m = 0; m < 4; ++m)
#pragma unroll
    for (int n = 0; n < 4; ++n) {
      f32x4 v = acc[m][n];
      int col = bn + wcol + n * 16 + l15;
      int row0 = bm + wrow + m * 16 + l4 * 4;
#pragma unroll
      for (int r = 0; r < 4; ++r) C[(size_t)(row0 + r) * DD + col] = v[r];
    }
}

// ------------- causal flash attention, bf16 MFMA, paired Q-tiles -----------
// R5 structure (KB=64, global_load_lds dbuf, 1 barrier/iter) + fused A/B
// phases (shared K/V LDS reads, 2x ILP on softmax chains) + XCD swizzle.

#define ATTN_SM(SC, OO, LS, MM, PS)                                              \
  do {                                                                           \
    float pm[4];                                                                 \
    _Pragma("unroll")                                                            \
    for (int r = 0; r < 4; ++r) {                                                \
      float tm = fmaxf(fmaxf(SC[0][r], SC[1][r]), fmaxf(SC[2][r], SC[3][r]));    \
      tm = fmaxf(tm, __shfl_xor(tm, 1));                                         \
      tm = fmaxf(tm, __shfl_xor(tm, 2));                                         \
      tm = fmaxf(tm, __shfl_xor(tm, 4));                                         \
      tm = fmaxf(tm, __shfl_xor(tm, 8));                                         \
      pm[r] = tm;                                                                 \
    }                                                                            \
    float growth = fmaxf(fmaxf(pm[0] - MM[0], pm[1] - MM[1]),                    \
                         fmaxf(pm[2] - MM[2], pm[3] - MM[3]));                   \
    if (!__all(growth <= 8.f)) {                                                 \
      _Pragma("unroll")                                                          \
      for (int r = 0; r < 4; ++r) {                                              \
        float mn = fmaxf(MM[r], pm[r]);                                          \
        float corr = __builtin_amdgcn_exp2f(MM[r] - mn);                         \
        MM[r] = mn;                                                              \
        OO[0][r] *= corr; OO[1][r] *= corr; OO[2][r] *= corr; OO[3][r] *= corr;  \
        LS[r] *= corr;                                                           \
      }                                                                          \
    }                                                                            \
    _Pragma("unroll")                                                            \
    for (int r = 0; r < 4; ++r) {                                                \
      const int pr = (w * 16 + l4 * 4 + r) * 72;                                 \
      _Pragma("unroll")                                                          \
      for (int n = 0; n < 4; ++n)                                                \
        PS[pr + n * 16 + l15] = f2bf(__builtin_amdgcn_exp2f(SC[n][r] - MM[r]));  \
    }                                                                            \
  } while (0)

#define ATTN_EPI(OO, LS, QI)                                                     \
  do {                                                                           \
    _Pragma("unroll")                                                            \
    for (int r = 0; r < 4; ++r) {                                                \
      const float inv = 1.f / LS[r];                                             \
      const int orow = (QI) * 64 + w * 16 + l4 * 4 + r;                          \
      const size_t ob = ((size_t)b * SS + orow) * DD + h * HDD + l15;            \
      _Pragma("unroll")                                                          \
      for (int n = 0; n < 4; ++n)                                                \
        Ohi[ob + n * 16] = f2bf(OO[n][r] * inv);                                 \
    }                                                                            \
  } while (0)

__global__ __launch_bounds__(256) void attn_mfma_kernel(
    const unsigned short* __restrict__ Qhi, const unsigned short* __restrict__ Qlo,
    const unsigned short* __restrict__ Khi_g, const unsigned short* __restrict__ Vt_g,
    unsigned short* __restrict__ Ohi) {
  __shared__ __align__(16) unsigned short Ks[2][64 * 64];
  __shared__ __align__(16) unsigned short Vs[2][64 * 64];
  __shared__ __align__(16) unsigned short PsA[64 * 72];
  __shared__ __align__(16) unsigned short PsB[64 * 72];

  const int t = threadIdx.x;
  const int lane = t & 63;
  const int w = t >> 6;
  // XCD-aware swizzle: flat = by*16+bx; xcd = flat&7 owns 4 heads -> K/V in L2
  const int flat = (int)blockIdx.y * 16 + (int)blockIdx.x;
  const int p = flat >> 5;                          // 0..15
  const int bh = ((flat & 7) << 2) | ((flat >> 3) & 3);  // 0..31, 4 heads/XCD
  const int qiA = 31 - p, qiB = p;                  // long + short tile
  const int b = bh >> 4, h = bh & 15;
  const int l15 = lane & 15, l4 = lane >> 4, l7 = lane & 7;

  s16x8 qhA[2], qlA[2], qhB[2], qlB[2];
  {
    const int rowA = qiA * 64 + w * 16 + l15;
    const unsigned short* qb = Qhi + ((size_t)bh * SS + rowA) * HDD + 8 * l4;
    const unsigned short* qc = Qlo + ((size_t)bh * SS + rowA) * HDD + 8 * l4;
    qhA[0] = *(const s16x8*)(qb);
    qhA[1] = *(const s16x8*)(qb + 32);
    qlA[0] = *(const s16x8*)(qc);
    qlA[1] = *(const s16x8*)(qc + 32);
    const int rowB = qiB * 64 + w * 16 + l15;
    const unsigned short* qd = Qhi + ((size_t)bh * SS + rowB) * HDD + 8 * l4;
    const unsigned short* qe = Qlo + ((size_t)bh * SS + rowB) * HDD + 8 * l4;
    qhB[0] = *(const s16x8*)(qd);
    qhB[1] = *(const s16x8*)(qd + 32);
    qlB[0] = *(const s16x8*)(qe);
    qlB[1] = *(const s16x8*)(qe + 32);
  }

  // staging maps: linear LDS dest, inverse-swizzled global source (rule #21)
  int lds[2];
  size_t koff[2], voff[2];
#pragma unroll
  for (int c = 0; c < 2; ++c) {
    int G = t + c * 256;
    int row = G >> 3, g = G & 7;
    int gs = g ^ (row & 7);
    lds[c] = G * 8;
    koff[c] = ((size_t)bh * SS + row) * HDD + gs * 8;
    voff[c] = ((size_t)bh * HDD + row) * SS + gs * 8;
  }

  const f32x4 z = {0.f, 0.f, 0.f, 0.f};
  f32x4 oA[4], oB[4], lsA = z, lsB = z;
#pragma unroll
  for (int n = 0; n < 4; ++n) { oA[n] = z; oB[n] = z; }
  float mA[4], mB[4];
#pragma unroll
  for (int r = 0; r < 4; ++r) { mA[r] = -INFINITY; mB[r] = -INFINITY; }

  const short one_bf = (short)0x3F80;
  const s16x8 ones = {one_bf, one_bf, one_bf, one_bf, one_bf, one_bf, one_bf, one_bf};

  // prologue: stage tile 0 into buffer 0
#pragma unroll
  for (int c = 0; c < 2; ++c) {
    GLDS16(Khi_g + koff[c], &Ks[0][lds[c]]);
    GLDS16(Vt_g + voff[c], &Vs[0][lds[c]]);
  }
  __syncthreads();

  int cur = 0;
  for (int kt = 0; kt <= qiA; ++kt) {
    const bool doB = kt <= qiB;
    if (kt < qiA) {  // prefetch next tile (runs concurrently with compute)
      const size_t ka = (size_t)(kt + 1) * 64 * HDD;
      const size_t va = (size_t)(kt + 1) * 64;
      const int nxt = cur ^ 1;
#pragma unroll
      for (int c = 0; c < 2; ++c) {
        GLDS16(Khi_g + ka + koff[c], &Ks[nxt][lds[c]]);
        GLDS16(Vt_g + va + voff[c], &Vs[nxt][lds[c]]);
      }
    }

    // ---- QK^T fused: each kh feeds A and B ----
    f32x4 scA[4], scB[4];
#pragma unroll
    for (int n = 0; n < 4; ++n) { scA[n] = z; scB[n] = z; }
    __builtin_amdgcn_s_setprio(1);
#pragma unroll
    for (int kc = 0; kc < 2; ++kc) {
      const int swz = ((kc * 4 + l4) ^ l7) * 8;
#pragma unroll
      for (int n = 0; n < 4; ++n) {
        const s16x8 kh = *(const s16x8*)&Ks[cur][(n * 16 + l15) * 64 + swz];
        scA[n] = __builtin_amdgcn_mfma_f32_16x16x32_bf16(qhA[kc], kh, scA[n], 0, 0, 0);
        scA[n] = __builtin_amdgcn_mfma_f32_16x16x32_bf16(qlA[kc], kh, scA[n], 0, 0, 0);
        if (doB) {
          scB[n] = __builtin_amdgcn_mfma_f32_16x16x32_bf16(qhB[kc], kh, scB[n], 0, 0, 0);
          scB[n] = __builtin_amdgcn_mfma_f32_16x16x32_bf16(qlB[kc], kh, scB[n], 0, 0, 0);
        }
      }
    }
    __builtin_amdgcn_s_setprio(0);

    // ---- masks (diagonal tiles) ----
    if (kt == qiA) {
#pragma unroll
      for (int n = 0; n < 4; ++n)
#pragma unroll
        for (int r = 0; r < 4; ++r)
          if (n * 16 + l15 > w * 16 + l4 * 4 + r) scA[n][r] = -INFINITY;
    }
    if (kt == qiB) {
#pragma unroll
      for (int n = 0; n < 4; ++n)
#pragma unroll
        for (int r = 0; r < 4; ++r)
          if (n * 16 + l15 > w * 16 + l4 * 4 + r) scB[n][r] = -INFINITY;
    }

    // ---- softmax: two independent chains, compiler interleaves ----
    ATTN_SM(scA, oA, lsA, mA, PsA);
    if (doB) ATTN_SM(scB, oB, lsB, mB, PsB);

    // ---- PV fused: each vb feeds A and B ----
    const int prow = (w * 16 + l15) * 72;
    __builtin_amdgcn_s_setprio(1);
#pragma unroll
    for (int c = 0; c < 2; ++c) {
      const s16x8 paA = *(const s16x8*)&PsA[prow + c * 32 + 8 * l4];
      const int swz = ((c * 4 + l4) ^ l7) * 8;
#pragma unroll
      for (int n = 0; n < 4; ++n) {
        const s16x8 vb = *(const s16x8*)&Vs[cur][(n * 16 + l15) * 64 + swz];
        oA[n] = __builtin_amdgcn_mfma_f32_16x16x32_bf16(paA, vb, oA[n], 0, 0, 0);
        if (doB) {
          const s16x8 paB = *(const s16x8*)&PsB[prow + c * 32 + 8 * l4];
          oB[n] = __builtin_amdgcn_mfma_f32_16x16x32_bf16(paB, vb, oB[n], 0, 0, 0);
        }
      }
      lsA = __builtin_amdgcn_mfma_f32_16x16x32_bf16(paA, ones, lsA, 0, 0, 0);
      if (doB) {
        const s16x8 paB = *(const s16x8*)&PsB[prow + c * 32 + 8 * l4];
        lsB = __builtin_amdgcn_mfma_f32_16x16x32_bf16(paB, ones, lsB, 0, 0, 0);
      }
    }
    __builtin_amdgcn_s_setprio(0);

    __syncthreads();  // drains prefetch vmcnt; protects buffer swap
    cur ^= 1;
  }

  ATTN_EPI(oA, lsA, qiA);
  ATTN_EPI(oB, lsB, qiB);
}

extern "C" void kernel_launch(void* const* d_in, const int* in_sizes, int n_in,
                              void* d_out, int out_size, void* d_ws, size_t ws_size,
                              hipStream_t stream) {
  const float* query = (const float*)d_in[0];
  const float* sin_q = (const float*)d_in[1];
  const float* cos_q = (const float*)d_in[2];
  const float* sin_k = (const float*)d_in[3];
  const float* cos_k = (const float*)d_in[4];
  const float* w_in  = (const float*)d_in[5];
  const float* w_out = (const float*)d_in[6];
  float* out = (float*)d_out;

  const int M = BB * SS;  // 4096
  const size_t MD = (size_t)M * DD;

  unsigned char* ws = (unsigned char*)d_ws;
  size_t off = 0;
  unsigned short* Qb  = (unsigned short*)(ws + off); off += MD * 2;
  unsigned short* B1h = (unsigned short*)(ws + off); off += (size_t)DD * 3 * DD * 2;
  unsigned short* B1l = (unsigned short*)(ws + off); off += (size_t)DD * 3 * DD * 2;
  unsigned short* B2h = (unsigned short*)(ws + off); off += (size_t)DD * DD * 2;
  unsigned short* B2l = (unsigned short*)(ws + off); off += (size_t)DD * DD * 2;
  unsigned short* Qhi = (unsigned short*)(ws + off); off += MD * 2;
  unsigned short* Qlo = (unsigned short*)(ws + off); off += MD * 2;
  unsigned short* Khi = (unsigned short*)(ws + off); off += MD * 2;
  unsigned short* Vt  = (unsigned short*)(ws + off); off += MD * 2;
  unsigned short* Ohi = (unsigned short*)(ws + off); off += MD * 2;

  {  // pre-pass: A cast + weight splits
    int n4 = (int)(MD / 4);
    cast_bf16_kernel<<<(n4 + 255) / 256, 256, 0, stream>>>(query, Qb, n4);
    split_transpose_kernel<<<dim3(3 * DD / 64, DD / 64), 256, 0, stream>>>(w_in, B1h, B1l, DD, 3 * DD);
    split_transpose_kernel<<<dim3(DD / 64, DD / 64), 256, 0, stream>>>(w_out, B2h, B2l, DD, DD);
  }
  {  // 1) fused QKV projection + RoPE + head-split + V-transpose
    dim3 grid((3 * DD) / 128, M / 128);
    gemm_qkv_rope_kernel<<<grid, 256, 0, stream>>>(
        Qb, B1h, B1l, sin_q, cos_q, sin_k, cos_k, Qhi, Qlo, Khi, Vt);
  }
  {  // 2) causal attention (MFMA, paired tiles, dbuf, fused A/B, XCD swizzle)
    dim3 grid(SS / 128, BB * HH);
    attn_mfma_kernel<<<grid, 256, 0, stream>>>(Qhi, Qlo, Khi, Vt, Ohi);
  }
  {  // 3) output projection
    dim3 grid(DD / 128, M / 128);
    gemm_out_kernel<<<grid, 256, 0, stream>>>(Ohi, B2h, B2l, out);
  }
}

// Round 8
// 222.614 us; speedup vs baseline: 1.1989x; 1.1624x over previous
//
#include <hip/hip_runtime.h>
#include <hip/hip_bf16.h>
#include <math.h>

#define BB 2
#define SS 2048
#define DD 1024
#define HH 16
#define HDD 64

typedef float f32x4 __attribute__((ext_vector_type(4)));
typedef short s16x8 __attribute__((ext_vector_type(8)));
typedef unsigned short u16x8 __attribute__((ext_vector_type(8)));

__device__ inline unsigned short f2bf(float x) {
  union { __hip_bfloat16 b; unsigned short u; } cv;
  cv.b = __float2bfloat16(x);  // RNE; compiles to HW cvt op (m240)
  return cv.u;
}
__device__ inline float bf2f(unsigned short h) {
  return __uint_as_float(((unsigned)h) << 16);
}

// ---------------- pre-pass: cast fp32 -> bf16 (A operand, hi only) ---------
__global__ __launch_bounds__(256) void cast_bf16_kernel(const float* __restrict__ X,
                                                        unsigned short* __restrict__ Xb,
                                                        int n4) {
  int i = blockIdx.x * 256 + threadIdx.x;
  if (i >= n4) return;
  float4 v = ((const float4*)X)[i];
  ushort4 h;
  h.x = f2bf(v.x); h.y = f2bf(v.y); h.z = f2bf(v.z); h.w = f2bf(v.w);
  ((ushort4*)Xb)[i] = h;
}

// -------- pre-pass: cast + transpose W[K][N] -> WT [N][K] (hi only) --------
__global__ __launch_bounds__(256) void cast_transpose_kernel(
    const float* __restrict__ W, unsigned short* __restrict__ WT, int K, int N) {
  __shared__ float tile[64][65];
  const int k0 = blockIdx.y * 64, n0 = blockIdx.x * 64;
  const int t = threadIdx.x;
  const int c = t & 63, rq = t >> 6;
#pragma unroll
  for (int u = 0; u < 16; ++u) {
    int r = u * 4 + rq;
    tile[r][c] = W[(size_t)(k0 + r) * N + n0 + c];
  }
  __syncthreads();
#pragma unroll
  for (int u = 0; u < 16; ++u) {
    int nl = u * 4 + rq;
    WT[(size_t)(n0 + nl) * K + k0 + c] = f2bf(tile[c][nl]);
  }
}

// -------- pre-pass: split + transpose W[K][N] -> WT_h/WT_l [N][K] ----------
__global__ __launch_bounds__(256) void split_transpose_kernel(
    const float* __restrict__ W, unsigned short* __restrict__ WTh,
    unsigned short* __restrict__ WTl, int K, int N) {
  __shared__ float tile[64][65];
  const int k0 = blockIdx.y * 64, n0 = blockIdx.x * 64;
  const int t = threadIdx.x;
  const int c = t & 63, rq = t >> 6;
#pragma unroll
  for (int u = 0; u < 16; ++u) {
    int r = u * 4 + rq;
    tile[r][c] = W[(size_t)(k0 + r) * N + n0 + c];
  }
  __syncthreads();
#pragma unroll
  for (int u = 0; u < 16; ++u) {
    int nl = u * 4 + rq;
    float v = tile[c][nl];  // = W[k0+c][n0+nl]
    unsigned short h = f2bf(v);
    unsigned short l = f2bf(v - bf2f(h));
    size_t o = (size_t)(n0 + nl) * K + k0 + c;
    WTh[o] = h;
    WTl[o] = l;
  }
}

#define GLDS16(g, l)                                                        \
  __builtin_amdgcn_global_load_lds(                                         \
      (const __attribute__((address_space(1))) unsigned int*)(const void*)(g), \
      (__attribute__((address_space(3))) unsigned int*)(l), 16, 0, 0)

// =================== 1-term GEMM core (A bf16, B bf16) =====================
#define GEMM1T_PRE(Ab, BTh, Kdim)                                           \
  const int t = threadIdx.x;                                                \
  const int bm = blockIdx.y * 128;                                          \
  const int bn = blockIdx.x * 128;                                          \
  const int w = t >> 6, lane = t & 63;                                      \
  const int wrow = (w >> 1) * 64, wcol = (w & 1) * 64;                      \
  const int l15 = lane & 15, l4 = lane >> 4, l7 = lane & 7;                 \
  int ldsoff[4];                                                            \
  const unsigned short* pA[4];                                              \
  const unsigned short* pBh[4];                                             \
  _Pragma("unroll")                                                         \
  for (int cc = 0; cc < 4; ++cc) {                                          \
    int tp = t + cc * 256;                                                  \
    int srow = tp >> 3;                                                     \
    int gq = (tp & 7) ^ (srow & 7);                                         \
    ldsoff[cc] = tp * 8;                                                    \
    pA[cc]  = (Ab)  + (size_t)(bm + srow) * (Kdim) + gq * 8;                \
    pBh[cc] = (BTh) + (size_t)(bn + srow) * (Kdim) + gq * 8;                \
  }                                                                         \
  f32x4 acc[4][4];                                                          \
  const f32x4 z = {0.f, 0.f, 0.f, 0.f};                                     \
  _Pragma("unroll")                                                         \
  for (int m = 0; m < 4; ++m)                                               \
    _Pragma("unroll")                                                       \
    for (int n = 0; n < 4; ++n) acc[m][n] = z;                              \
  for (int k0 = 0; k0 < (Kdim); k0 += 64) {                                 \
    __syncthreads();                                                        \
    _Pragma("unroll")                                                       \
    for (int cc = 0; cc < 4; ++cc) {                                        \
      GLDS16(pA[cc] + k0, &As_b[ldsoff[cc]]);                               \
      GLDS16(pBh[cc] + k0, &Bs_h[ldsoff[cc]]);                              \
    }                                                                       \
    __syncthreads();                                                        \
    _Pragma("unroll")                                                       \
    for (int ks = 0; ks < 2; ++ks) {                                        \
      const int sw = ((ks * 4 + l4) ^ l7) * 8;                              \
      s16x8 a[4], bh[4];                                                    \
      _Pragma("unroll")                                                     \
      for (int m = 0; m < 4; ++m)                                           \
        a[m] = *(const s16x8*)&As_b[(wrow + m * 16 + l15) * 64 + sw];       \
      _Pragma("unroll")                                                     \
      for (int n = 0; n < 4; ++n)                                           \
        bh[n] = *(const s16x8*)&Bs_h[(wcol + n * 16 + l15) * 64 + sw];      \
      _Pragma("unroll")                                                     \
      for (int m = 0; m < 4; ++m)                                           \
        _Pragma("unroll")                                                   \
        for (int n = 0; n < 4; ++n)                                         \
          acc[m][n] = __builtin_amdgcn_mfma_f32_16x16x32_bf16(a[m], bh[n], acc[m][n], 0, 0, 0); \
    }                                                                       \
  }

// =================== 2-term GEMM core (A bf16, B hi/lo) ====================
#define GEMM2T_PRE(Ab, BTh, BTl, Kdim)                                     \
  const int t = threadIdx.x;                                                \
  const int bm = blockIdx.y * 128;                                          \
  const int bn = blockIdx.x * 128;                                          \
  const int w = t >> 6, lane = t & 63;                                      \
  const int wrow = (w >> 1) * 64, wcol = (w & 1) * 64;                      \
  const int l15 = lane & 15, l4 = lane >> 4, l7 = lane & 7;                 \
  int ldsoff[4];                                                            \
  const unsigned short* pA[4];                                              \
  const unsigned short* pBh[4];                                             \
  const unsigned short* pBl[4];                                             \
  _Pragma("unroll")                                                         \
  for (int cc = 0; cc < 4; ++cc) {                                          \
    int tp = t + cc * 256;                                                  \
    int srow = tp >> 3;                                                     \
    int gq = (tp & 7) ^ (srow & 7);                                         \
    ldsoff[cc] = tp * 8;                                                    \
    pA[cc]  = (Ab)  + (size_t)(bm + srow) * (Kdim) + gq * 8;                \
    pBh[cc] = (BTh) + (size_t)(bn + srow) * (Kdim) + gq * 8;                \
    pBl[cc] = (BTl) + (size_t)(bn + srow) * (Kdim) + gq * 8;                \
  }                                                                         \
  f32x4 acc[4][4];                                                          \
  const f32x4 z = {0.f, 0.f, 0.f, 0.f};                                     \
  _Pragma("unroll")                                                         \
  for (int m = 0; m < 4; ++m)                                               \
    _Pragma("unroll")                                                       \
    for (int n = 0; n < 4; ++n) acc[m][n] = z;                              \
  for (int k0 = 0; k0 < (Kdim); k0 += 64) {                                 \
    __syncthreads();                                                        \
    _Pragma("unroll")                                                       \
    for (int cc = 0; cc < 4; ++cc) {                                        \
      GLDS16(pA[cc] + k0, &As_b[ldsoff[cc]]);                               \
      GLDS16(pBh[cc] + k0, &Bs_h[ldsoff[cc]]);                              \
      GLDS16(pBl[cc] + k0, &Bs_l[ldsoff[cc]]);                              \
    }                                                                       \
    __syncthreads();                                                        \
    _Pragma("unroll")                                                       \
    for (int ks = 0; ks < 2; ++ks) {                                        \
      const int sw = ((ks * 4 + l4) ^ l7) * 8;                              \
      s16x8 a[4], bh[4], bl[4];                                             \
      _Pragma("unroll")                                                     \
      for (int m = 0; m < 4; ++m)                                           \
        a[m] = *(const s16x8*)&As_b[(wrow + m * 16 + l15) * 64 + sw];       \
      _Pragma("unroll")                                                     \
      for (int n = 0; n < 4; ++n) {                                         \
        int idx = (wcol + n * 16 + l15) * 64 + sw;                          \
        bh[n] = *(const s16x8*)&Bs_h[idx];                                  \
        bl[n] = *(const s16x8*)&Bs_l[idx];                                  \
      }                                                                     \
      _Pragma("unroll")                                                     \
      for (int m = 0; m < 4; ++m)                                           \
        _Pragma("unroll")                                                   \
        for (int n = 0; n < 4; ++n) {                                       \
          acc[m][n] = __builtin_amdgcn_mfma_f32_16x16x32_bf16(a[m], bh[n], acc[m][n], 0, 0, 0); \
          acc[m][n] = __builtin_amdgcn_mfma_f32_16x16x32_bf16(a[m], bl[n], acc[m][n], 0, 0, 0); \
        }                                                                   \
    }                                                                       \
  }

// ---- GEMM1: fused QKV proj + RoPE + head-split + V-transpose (1-term) -----
__global__ __launch_bounds__(256) void gemm_qkv_rope_kernel(
    const unsigned short* __restrict__ Ab,
    const unsigned short* __restrict__ BTh,
    const float* __restrict__ sin_q, const float* __restrict__ cos_q,
    const float* __restrict__ sin_k, const float* __restrict__ cos_k,
    unsigned short* __restrict__ Qhi, unsigned short* __restrict__ Qlo,
    unsigned short* __restrict__ Khi, unsigned short* __restrict__ Vt) {
  __shared__ __align__(16) unsigned short As_b[128 * 64];
  __shared__ __align__(16) unsigned short Bs_h[128 * 64];
  GEMM1T_PRE(Ab, BTh, DD)

  const int region = bn >> 10;
  const int hloc = ((bn & 1023) + wcol) >> 6;
  const float QSC = 0.125f * 1.44269504088896340736f;  // 1/sqrt(HD) * log2(e)

  if (region == 0) {  // Q: rope, scale, split hi/lo
#pragma unroll
    for (int m = 0; m < 4; ++m) {
      const int row0 = bm + wrow + m * 16 + l4 * 4;
#pragma unroll
      for (int r = 0; r < 4; ++r) {
        const int row = row0 + r, b = row >> 11, s = row & 2047;
        const size_t ob = ((size_t)(b * HH + hloc) * SS + s) * HDD;
        const float* cq = cos_q + s * HDD;
        const float* sq = sin_q + s * HDD;
#pragma unroll
        for (int np = 0; np < 2; ++np) {
          const int d1 = np * 16 + l15;
          float x1 = acc[m][np][r], x2 = acc[m][np + 2][r];
          float q1 = (x1 * cq[d1] - x2 * sq[d1]) * QSC;
          float q2 = (x2 * cq[d1 + 32] + x1 * sq[d1 + 32]) * QSC;
          unsigned short h1 = f2bf(q1), h2 = f2bf(q2);
          Qhi[ob + d1] = h1;      Qlo[ob + d1] = f2bf(q1 - bf2f(h1));
          Qhi[ob + d1 + 32] = h2; Qlo[ob + d1 + 32] = f2bf(q2 - bf2f(h2));
        }
      }
    }
  } else if (region == 1) {  // K: rope, single bf16
#pragma unroll
    for (int m = 0; m < 4; ++m) {
      const int row0 = bm + wrow + m * 16 + l4 * 4;
#pragma unroll
      for (int r = 0; r < 4; ++r) {
        const int row = row0 + r, b = row >> 11, s = row & 2047;
        const size_t ob = ((size_t)(b * HH + hloc) * SS + s) * HDD;
        const float* ck = cos_k + s * HDD;
        const float* sk = sin_k + s * HDD;
#pragma unroll
        for (int np = 0; np < 2; ++np) {
          const int d1 = np * 16 + l15;
          float x1 = acc[m][np][r], x2 = acc[m][np + 2][r];
          Khi[ob + d1]      = f2bf(x1 * ck[d1] - x2 * sk[d1]);
          Khi[ob + d1 + 32] = f2bf(x2 * ck[d1 + 32] + x1 * sk[d1 + 32]);
        }
      }
    }
  } else {  // V: transpose to [B,H,HD,S]
#pragma unroll
    for (int m = 0; m < 4; ++m) {
      const int row0 = bm + wrow + m * 16 + l4 * 4;
      const int b = row0 >> 11, s0 = row0 & 2047;
#pragma unroll
      for (int n = 0; n < 4; ++n) {
        const int d = n * 16 + l15;
        ushort4 v4;
        v4.x = f2bf(acc[m][n][0]);
        v4.y = f2bf(acc[m][n][1]);
        v4.z = f2bf(acc[m][n][2]);
        v4.w = f2bf(acc[m][n][3]);
        *(ushort4*)&Vt[((size_t)(b * HH + hloc) * HDD + d) * SS + s0] = v4;
      }
    }
  }
}

// ---- GEMM2: output projection, 2-term, fp32 C ----
__global__ __launch_bounds__(256) void gemm_out_kernel(
    const unsigned short* __restrict__ Ab,
    const unsigned short* __restrict__ BTh, const unsigned short* __restrict__ BTl,
    float* __restrict__ C) {
  __shared__ __align__(16) unsigned short As_b[128 * 64];
  __shared__ __align__(16) unsigned short Bs_h[128 * 64];
  __shared__ __align__(16) unsigned short Bs_l[128 * 64];
  GEMM2T_PRE(Ab, BTh, BTl, DD)

#pragma unroll
  for (int m = 0; m < 4; ++m)
#pragma unroll
    for (int n = 0; n < 4; ++n) {
      f32x4 v = acc[m][n];
      int col = bn + wcol + n * 16 + l15;
      int row0 = bm + wrow + m * 16 + l4 * 4;
#pragma unroll
      for (int r = 0; r < 4; ++r) C[(size_t)(row0 + r) * DD + col] = v[r];
    }
}

// ------------- causal flash attention: R5 body + XCD swizzle ---------------
#define ATTN_TILE(QH, QL, OO, LS, MM, MASKED, CUR)                               \
  do {                                                                           \
    f32x4 sc[4];                                                                 \
    sc[0] = z; sc[1] = z; sc[2] = z; sc[3] = z;                                  \
    __builtin_amdgcn_s_setprio(1);                                               \
    _Pragma("unroll")                                                            \
    for (int kc = 0; kc < 2; ++kc) {                                             \
      const int swz = ((kc * 4 + l4) ^ l7) * 8;                                  \
      _Pragma("unroll")                                                          \
      for (int n = 0; n < 4; ++n) {                                              \
        const int idx = (n * 16 + l15) * 64 + swz;                               \
        s16x8 kh = *(const s16x8*)&Ks[CUR][idx];                                 \
        sc[n] = __builtin_amdgcn_mfma_f32_16x16x32_bf16(QH[kc], kh, sc[n], 0, 0, 0); \
        sc[n] = __builtin_amdgcn_mfma_f32_16x16x32_bf16(QL[kc], kh, sc[n], 0, 0, 0); \
      }                                                                          \
    }                                                                            \
    __builtin_amdgcn_s_setprio(0);                                               \
    if (MASKED) {                                                                \
      _Pragma("unroll")                                                          \
      for (int n = 0; n < 4; ++n)                                                \
        _Pragma("unroll")                                                        \
        for (int r = 0; r < 4; ++r)                                              \
          if (n * 16 + l15 > w * 16 + l4 * 4 + r) sc[n][r] = -INFINITY;          \
    }                                                                            \
    float pm[4];                                                                 \
    _Pragma("unroll")                                                            \
    for (int r = 0; r < 4; ++r) {                                                \
      float tm = fmaxf(fmaxf(sc[0][r], sc[1][r]), fmaxf(sc[2][r], sc[3][r]));    \
      tm = fmaxf(tm, __shfl_xor(tm, 1));                                         \
      tm = fmaxf(tm, __shfl_xor(tm, 2));                                         \
      tm = fmaxf(tm, __shfl_xor(tm, 4));                                         \
      tm = fmaxf(tm, __shfl_xor(tm, 8));                                         \
      pm[r] = tm;                                                                 \
    }                                                                            \
    float growth = fmaxf(fmaxf(pm[0] - MM[0], pm[1] - MM[1]),                    \
                         fmaxf(pm[2] - MM[2], pm[3] - MM[3]));                   \
    if (!__all(growth <= 8.f)) {                                                 \
      _Pragma("unroll")                                                          \
      for (int r = 0; r < 4; ++r) {                                              \
        float mn = fmaxf(MM[r], pm[r]);                                          \
        float corr = __builtin_amdgcn_exp2f(MM[r] - mn);                         \
        MM[r] = mn;                                                              \
        OO[0][r] *= corr; OO[1][r] *= corr; OO[2][r] *= corr; OO[3][r] *= corr;  \
        LS[r] *= corr;                                                           \
      }                                                                          \
    }                                                                            \
    _Pragma("unroll")                                                            \
    for (int r = 0; r < 4; ++r) {                                                \
      const int pr = (w * 16 + l4 * 4 + r) * 72;                                 \
      _Pragma("unroll")                                                          \
      for (int n = 0; n < 4; ++n)                                                \
        Ps[pr + n * 16 + l15] = f2bf(__builtin_amdgcn_exp2f(sc[n][r] - MM[r]));  \
    }                                                                            \
    const int prow = (w * 16 + l15) * 72;                                        \
    __builtin_amdgcn_s_setprio(1);                                               \
    _Pragma("unroll")                                                            \
    for (int c = 0; c < 2; ++c) {                                                \
      s16x8 pa = *(const s16x8*)&Ps[prow + c * 32 + 8 * l4];                     \
      const int swz = ((c * 4 + l4) ^ l7) * 8;                                   \
      _Pragma("unroll")                                                          \
      for (int n = 0; n < 4; ++n) {                                              \
        s16x8 vb = *(const s16x8*)&Vs[CUR][(n * 16 + l15) * 64 + swz];           \
        OO[n] = __builtin_amdgcn_mfma_f32_16x16x32_bf16(pa, vb, OO[n], 0, 0, 0); \
      }                                                                          \
      LS = __builtin_amdgcn_mfma_f32_16x16x32_bf16(pa, ones, LS, 0, 0, 0);       \
    }                                                                            \
    __builtin_amdgcn_s_setprio(0);                                               \
  } while (0)

#define ATTN_EPI(OO, LS, QI)                                                     \
  do {                                                                           \
    _Pragma("unroll")                                                            \
    for (int r = 0; r < 4; ++r) {                                                \
      const float inv = 1.f / LS[r];                                             \
      const int orow = (QI) * 64 + w * 16 + l4 * 4 + r;                          \
      const size_t ob = ((size_t)b * SS + orow) * DD + h * HDD + l15;            \
      _Pragma("unroll")                                                          \
      for (int n = 0; n < 4; ++n)                                                \
        Ohi[ob + n * 16] = f2bf(OO[n][r] * inv);                                 \
    }                                                                            \
  } while (0)

__global__ __launch_bounds__(256) void attn_mfma_kernel(
    const unsigned short* __restrict__ Qhi, const unsigned short* __restrict__ Qlo,
    const unsigned short* __restrict__ Khi_g, const unsigned short* __restrict__ Vt_g,
    unsigned short* __restrict__ Ohi) {
  __shared__ __align__(16) unsigned short Ks[2][64 * 64];
  __shared__ __align__(16) unsigned short Vs[2][64 * 64];
  __shared__ __align__(16) unsigned short Ps[64 * 72];

  const int t = threadIdx.x;
  const int lane = t & 63;
  const int w = t >> 6;
  // XCD-aware swizzle (R7, FETCH 76->16.5MB): xcd = flat&7 owns 4 heads
  const int flat = (int)blockIdx.y * 16 + (int)blockIdx.x;
  const int p = flat >> 5;                               // 0..15
  const int bh = ((flat & 7) << 2) | ((flat >> 3) & 3);  // 0..31
  const int qiA = 31 - p, qiB = p;
  const int b = bh >> 4, h = bh & 15;
  const int l15 = lane & 15, l4 = lane >> 4, l7 = lane & 7;

  s16x8 qhA[2], qlA[2], qhB[2], qlB[2];
  {
    const int rowA = qiA * 64 + w * 16 + l15;
    const unsigned short* qb = Qhi + ((size_t)bh * SS + rowA) * HDD + 8 * l4;
    const unsigned short* qc = Qlo + ((size_t)bh * SS + rowA) * HDD + 8 * l4;
    qhA[0] = *(const s16x8*)(qb);
    qhA[1] = *(const s16x8*)(qb + 32);
    qlA[0] = *(const s16x8*)(qc);
    qlA[1] = *(const s16x8*)(qc + 32);
    const int rowB = qiB * 64 + w * 16 + l15;
    const unsigned short* qd = Qhi + ((size_t)bh * SS + rowB) * HDD + 8 * l4;
    const unsigned short* qe = Qlo + ((size_t)bh * SS + rowB) * HDD + 8 * l4;
    qhB[0] = *(const s16x8*)(qd);
    qhB[1] = *(const s16x8*)(qd + 32);
    qlB[0] = *(const s16x8*)(qe);
    qlB[1] = *(const s16x8*)(qe + 32);
  }

  // staging maps: linear LDS dest, inverse-swizzled global source (rule #21)
  int lds[2];
  size_t koff[2], voff[2];
#pragma unroll
  for (int c = 0; c < 2; ++c) {
    int G = t + c * 256;
    int row = G >> 3, g = G & 7;
    int gs = g ^ (row & 7);
    lds[c] = G * 8;
    koff[c] = ((size_t)bh * SS + row) * HDD + gs * 8;
    voff[c] = ((size_t)bh * HDD + row) * SS + gs * 8;
  }

  const f32x4 z = {0.f, 0.f, 0.f, 0.f};
  f32x4 oA[4], oB[4], lsA = z, lsB = z;
#pragma unroll
  for (int n = 0; n < 4; ++n) { oA[n] = z; oB[n] = z; }
  float mA[4], mB[4];
#pragma unroll
  for (int r = 0; r < 4; ++r) { mA[r] = -INFINITY; mB[r] = -INFINITY; }

  const short one_bf = (short)0x3F80;
  const s16x8 ones = {one_bf, one_bf, one_bf, one_bf, one_bf, one_bf, one_bf, one_bf};

  // prologue: stage tile 0 into buffer 0
#pragma unroll
  for (int c = 0; c < 2; ++c) {
    GLDS16(Khi_g + koff[c], &Ks[0][lds[c]]);
    GLDS16(Vt_g + voff[c], &Vs[0][lds[c]]);
  }
  __syncthreads();

  int cur = 0;
  for (int kt = 0; kt <= qiA; ++kt) {
    if (kt < qiA) {  // prefetch next tile (concurrent with compute)
      const size_t ka = (size_t)(kt + 1) * 64 * HDD;
      const size_t va = (size_t)(kt + 1) * 64;
      const int nxt = cur ^ 1;
#pragma unroll
      for (int c = 0; c < 2; ++c) {
        GLDS16(Khi_g + ka + koff[c], &Ks[nxt][lds[c]]);
        GLDS16(Vt_g + va + voff[c], &Vs[nxt][lds[c]]);
      }
    }
    ATTN_TILE(qhA, qlA, oA, lsA, mA, kt == qiA, cur);
    if (kt <= qiB) ATTN_TILE(qhB, qlB, oB, lsB, mB, kt == qiB, cur);
    __syncthreads();  // drains prefetch vmcnt; protects buffer swap
    cur ^= 1;
  }

  ATTN_EPI(oA, lsA, qiA);
  ATTN_EPI(oB, lsB, qiB);
}

extern "C" void kernel_launch(void* const* d_in, const int* in_sizes, int n_in,
                              void* d_out, int out_size, void* d_ws, size_t ws_size,
                              hipStream_t stream) {
  const float* query = (const float*)d_in[0];
  const float* sin_q = (const float*)d_in[1];
  const float* cos_q = (const float*)d_in[2];
  const float* sin_k = (const float*)d_in[3];
  const float* cos_k = (const float*)d_in[4];
  const float* w_in  = (const float*)d_in[5];
  const float* w_out = (const float*)d_in[6];
  float* out = (float*)d_out;

  const int M = BB * SS;  // 4096
  const size_t MD = (size_t)M * DD;

  unsigned char* ws = (unsigned char*)d_ws;
  size_t off = 0;
  unsigned short* Qb  = (unsigned short*)(ws + off); off += MD * 2;
  unsigned short* B1h = (unsigned short*)(ws + off); off += (size_t)DD * 3 * DD * 2;
  unsigned short* B2h = (unsigned short*)(ws + off); off += (size_t)DD * DD * 2;
  unsigned short* B2l = (unsigned short*)(ws + off); off += (size_t)DD * DD * 2;
  unsigned short* Qhi = (unsigned short*)(ws + off); off += MD * 2;
  unsigned short* Qlo = (unsigned short*)(ws + off); off += MD * 2;
  unsigned short* Khi = (unsigned short*)(ws + off); off += MD * 2;
  unsigned short* Vt  = (unsigned short*)(ws + off); off += MD * 2;
  unsigned short* Ohi = (unsigned short*)(ws + off); off += MD * 2;

  {  // pre-pass: A cast + weight transposes
    int n4 = (int)(MD / 4);
    cast_bf16_kernel<<<(n4 + 255) / 256, 256, 0, stream>>>(query, Qb, n4);
    cast_transpose_kernel<<<dim3(3 * DD / 64, DD / 64), 256, 0, stream>>>(w_in, B1h, DD, 3 * DD);
    split_transpose_kernel<<<dim3(DD / 64, DD / 64), 256, 0, stream>>>(w_out, B2h, B2l, DD, DD);
  }
  {  // 1) fused QKV projection + RoPE + head-split + V-transpose (1-term)
    dim3 grid((3 * DD) / 128, M / 128);
    gemm_qkv_rope_kernel<<<grid, 256, 0, stream>>>(
        Qb, B1h, sin_q, cos_q, sin_k, cos_k, Qhi, Qlo, Khi, Vt);
  }
  {  // 2) causal attention (R5 structure + XCD swizzle)
    dim3 grid(SS / 128, BB * HH);
    attn_mfma_kernel<<<grid, 256, 0, stream>>>(Qhi, Qlo, Khi, Vt, Ohi);
  }
  {  // 3) output projection (2-term)
    dim3 grid(DD / 128, M / 128);
    gemm_out_kernel<<<grid, 256, 0, stream>>>(Ohi, B2h, B2l, out);
  }
}

// Round 11
// 209.113 us; speedup vs baseline: 1.2762x; 1.0646x over previous
//
#include <hip/hip_runtime.h>
#include <hip/hip_bf16.h>
#include <math.h>

#define BB 2
#define SS 2048
#define DD 1024
#define HH 16
#define HDD 64

typedef float f32x4 __attribute__((ext_vector_type(4)));
typedef short s16x8 __attribute__((ext_vector_type(8)));
typedef unsigned short u16x8 __attribute__((ext_vector_type(8)));

__device__ inline unsigned short f2bf(float x) {
  union { __hip_bfloat16 b; unsigned short u; } cv;
  cv.b = __float2bfloat16(x);  // RNE; compiles to HW cvt op (m240)
  return cv.u;
}
__device__ inline float bf2f(unsigned short h) {
  return __uint_as_float(((unsigned)h) << 16);
}

// ---------------- pre-pass: cast fp32 -> bf16 (A operand) ------------------
__global__ __launch_bounds__(256) void cast_bf16_kernel(const float* __restrict__ X,
                                                        unsigned short* __restrict__ Xb,
                                                        int n4) {
  int i = blockIdx.x * 256 + threadIdx.x;
  if (i >= n4) return;
  float4 v = ((const float4*)X)[i];
  ushort4 h;
  h.x = f2bf(v.x); h.y = f2bf(v.y); h.z = f2bf(v.z); h.w = f2bf(v.w);
  ((ushort4*)Xb)[i] = h;
}

// -------- pre-pass: cast + transpose W[K][N] -> WT [N][K] (bf16) -----------
__global__ __launch_bounds__(256) void cast_transpose_kernel(
    const float* __restrict__ W, unsigned short* __restrict__ WT, int K, int N) {
  __shared__ float tile[64][65];
  const int k0 = blockIdx.y * 64, n0 = blockIdx.x * 64;
  const int t = threadIdx.x;
  const int c = t & 63, rq = t >> 6;
#pragma unroll
  for (int u = 0; u < 16; ++u) {
    int r = u * 4 + rq;
    tile[r][c] = W[(size_t)(k0 + r) * N + n0 + c];
  }
  __syncthreads();
#pragma unroll
  for (int u = 0; u < 16; ++u) {
    int nl = u * 4 + rq;
    WT[(size_t)(n0 + nl) * K + k0 + c] = f2bf(tile[c][nl]);
  }
}

#define GLDS16(g, l)                                                        \
  __builtin_amdgcn_global_load_lds(                                         \
      (const __attribute__((address_space(1))) unsigned int*)(const void*)(g), \
      (__attribute__((address_space(3))) unsigned int*)(l), 16, 0, 0)

// =================== 1-term GEMM core (A bf16, B bf16) =====================
// Staging maps: linear LDS dest, inverse-swizzled global source (rule #21).
#define GEMM1T_PRE(Ab, BTh, Kdim)                                           \
  const int t = threadIdx.x;                                                \
  const int bm = blockIdx.y * 128;                                          \
  const int bn = blockIdx.x * 128;                                          \
  const int w = t >> 6, lane = t & 63;                                      \
  const int wrow = (w >> 1) * 64, wcol = (w & 1) * 64;                      \
  const int l15 = lane & 15, l4 = lane >> 4, l7 = lane & 7;                 \
  int ldsoff[4];                                                            \
  const unsigned short* pA[4];                                              \
  const unsigned short* pBh[4];                                             \
  _Pragma("unroll")                                                         \
  for (int cc = 0; cc < 4; ++cc) {                                          \
    int tp = t + cc * 256;                                                  \
    int srow = tp >> 3;                                                     \
    int gq = (tp & 7) ^ (srow & 7);                                         \
    ldsoff[cc] = tp * 8;                                                    \
    pA[cc]  = (Ab)  + (size_t)(bm + srow) * (Kdim) + gq * 8;                \
    pBh[cc] = (BTh) + (size_t)(bn + srow) * (Kdim) + gq * 8;                \
  }                                                                         \
  f32x4 acc[4][4];                                                          \
  const f32x4 z = {0.f, 0.f, 0.f, 0.f};                                     \
  _Pragma("unroll")                                                         \
  for (int m = 0; m < 4; ++m)                                               \
    _Pragma("unroll")                                                       \
    for (int n = 0; n < 4; ++n) acc[m][n] = z;                              \
  for (int k0 = 0; k0 < (Kdim); k0 += 64) {                                 \
    __syncthreads();                                                        \
    _Pragma("unroll")                                                       \
    for (int cc = 0; cc < 4; ++cc) {                                        \
      GLDS16(pA[cc] + k0, &As_b[ldsoff[cc]]);                               \
      GLDS16(pBh[cc] + k0, &Bs_h[ldsoff[cc]]);                              \
    }                                                                       \
    __syncthreads();                                                        \
    _Pragma("unroll")                                                       \
    for (int ks = 0; ks < 2; ++ks) {                                        \
      const int sw = ((ks * 4 + l4) ^ l7) * 8;                              \
      s16x8 a[4], bh[4];                                                    \
      _Pragma("unroll")                                                     \
      for (int m = 0; m < 4; ++m)                                           \
        a[m] = *(const s16x8*)&As_b[(wrow + m * 16 + l15) * 64 + sw];       \
      _Pragma("unroll")                                                     \
      for (int n = 0; n < 4; ++n)                                           \
        bh[n] = *(const s16x8*)&Bs_h[(wcol + n * 16 + l15) * 64 + sw];      \
      _Pragma("unroll")                                                     \
      for (int m = 0; m < 4; ++m)                                           \
        _Pragma("unroll")                                                   \
        for (int n = 0; n < 4; ++n)                                         \
          acc[m][n] = __builtin_amdgcn_mfma_f32_16x16x32_bf16(a[m], bh[n], acc[m][n], 0, 0, 0); \
    }                                                                       \
  }

// ---- GEMM1: fused QKV proj + RoPE + head-split + V-transpose (1-term) -----
__global__ __launch_bounds__(256) void gemm_qkv_rope_kernel(
    const unsigned short* __restrict__ Ab,
    const unsigned short* __restrict__ BTh,
    const float* __restrict__ sin_q, const float* __restrict__ cos_q,
    const float* __restrict__ sin_k, const float* __restrict__ cos_k,
    unsigned short* __restrict__ Qhi, unsigned short* __restrict__ Qlo,
    unsigned short* __restrict__ Khi, unsigned short* __restrict__ Vt) {
  __shared__ __align__(16) unsigned short As_b[128 * 64];
  __shared__ __align__(16) unsigned short Bs_h[128 * 64];
  GEMM1T_PRE(Ab, BTh, DD)

  const int region = bn >> 10;
  const int hloc = ((bn & 1023) + wcol) >> 6;
  const float QSC = 0.125f * 1.44269504088896340736f;  // 1/sqrt(HD) * log2(e)

  if (region == 0) {  // Q: rope, scale, split hi/lo
#pragma unroll
    for (int m = 0; m < 4; ++m) {
      const int row0 = bm + wrow + m * 16 + l4 * 4;
#pragma unroll
      for (int r = 0; r < 4; ++r) {
        const int row = row0 + r, b = row >> 11, s = row & 2047;
        const size_t ob = ((size_t)(b * HH + hloc) * SS + s) * HDD;
        const float* cq = cos_q + s * HDD;
        const float* sq = sin_q + s * HDD;
#pragma unroll
        for (int np = 0; np < 2; ++np) {
          const int d1 = np * 16 + l15;
          float x1 = acc[m][np][r], x2 = acc[m][np + 2][r];
          float q1 = (x1 * cq[d1] - x2 * sq[d1]) * QSC;
          float q2 = (x2 * cq[d1 + 32] + x1 * sq[d1 + 32]) * QSC;
          unsigned short h1 = f2bf(q1), h2 = f2bf(q2);
          Qhi[ob + d1] = h1;      Qlo[ob + d1] = f2bf(q1 - bf2f(h1));
          Qhi[ob + d1 + 32] = h2; Qlo[ob + d1 + 32] = f2bf(q2 - bf2f(h2));
        }
      }
    }
  } else if (region == 1) {  // K: rope, single bf16
#pragma unroll
    for (int m = 0; m < 4; ++m) {
      const int row0 = bm + wrow + m * 16 + l4 * 4;
#pragma unroll
      for (int r = 0; r < 4; ++r) {
        const int row = row0 + r, b = row >> 11, s = row & 2047;
        const size_t ob = ((size_t)(b * HH + hloc) * SS + s) * HDD;
        const float* ck = cos_k + s * HDD;
        const float* sk = sin_k + s * HDD;
#pragma unroll
        for (int np = 0; np < 2; ++np) {
          const int d1 = np * 16 + l15;
          float x1 = acc[m][np][r], x2 = acc[m][np + 2][r];
          Khi[ob + d1]      = f2bf(x1 * ck[d1] - x2 * sk[d1]);
          Khi[ob + d1 + 32] = f2bf(x2 * ck[d1 + 32] + x1 * sk[d1 + 32]);
        }
      }
    }
  } else {  // V: transpose to [B,H,HD,S]
#pragma unroll
    for (int m = 0; m < 4; ++m) {
      const int row0 = bm + wrow + m * 16 + l4 * 4;
      const int b = row0 >> 11, s0 = row0 & 2047;
#pragma unroll
      for (int n = 0; n < 4; ++n) {
        const int d = n * 16 + l15;
        ushort4 v4;
        v4.x = f2bf(acc[m][n][0]);
        v4.y = f2bf(acc[m][n][1]);
        v4.z = f2bf(acc[m][n][2]);
        v4.w = f2bf(acc[m][n][3]);
        *(ushort4*)&Vt[((size_t)(b * HH + hloc) * HDD + d) * SS + s0] = v4;
      }
    }
  }
}

// ---- GEMM2: output projection, 1-term, fp32 C ----
__global__ __launch_bounds__(256) void gemm_out_kernel(
    const unsigned short* __restrict__ Ab,
    const unsigned short* __restrict__ BTh,
    float* __restrict__ C) {
  __shared__ __align__(16) unsigned short As_b[128 * 64];
  __shared__ __align__(16) unsigned short Bs_h[128 * 64];
  GEMM1T_PRE(Ab, BTh, DD)

#pragma unroll
  for (int m = 0; m < 4; ++m)
#pragma unroll
    for (int n = 0; n < 4; ++n) {
      f32x4 v = acc[m][n];
      int col = bn + wcol + n * 16 + l15;
      int row0 = bm + wrow + m * 16 + l4 * 4;
#pragma unroll
      for (int r = 0; r < 4; ++r) C[(size_t)(row0 + r) * DD + col] = v[r];
    }
}

// ------------- causal flash attention: unpaired Q-tiles, 1024 blocks -------
// R5 tile body; one 64-row Q-tile per block; long blocks dispatch first;
// XCD swizzle keeps 4 heads per XCD (K/V 2MB within 4MB L2).

#define ATTN_TILE(QH, QL, OO, LS, MM, MASKED, CUR)                               \
  do {                                                                           \
    f32x4 sc[4];                                                                 \
    sc[0] = z; sc[1] = z; sc[2] = z; sc[3] = z;                                  \
    __builtin_amdgcn_s_setprio(1);                                               \
    _Pragma("unroll")                                                            \
    for (int kc = 0; kc < 2; ++kc) {                                             \
      const int swz = ((kc * 4 + l4) ^ l7) * 8;                                  \
      _Pragma("unroll")                                                          \
      for (int n = 0; n < 4; ++n) {                                              \
        const int idx = (n * 16 + l15) * 64 + swz;                               \
        s16x8 kh = *(const s16x8*)&Ks[CUR][idx];                                 \
        sc[n] = __builtin_amdgcn_mfma_f32_16x16x32_bf16(QH[kc], kh, sc[n], 0, 0, 0); \
        sc[n] = __builtin_amdgcn_mfma_f32_16x16x32_bf16(QL[kc], kh, sc[n], 0, 0, 0); \
      }                                                                          \
    }                                                                            \
    __builtin_amdgcn_s_setprio(0);                                               \
    if (MASKED) {                                                                \
      _Pragma("unroll")                                                          \
      for (int n = 0; n < 4; ++n)                                                \
        _Pragma("unroll")                                                        \
        for (int r = 0; r < 4; ++r)                                              \
          if (n * 16 + l15 > w * 16 + l4 * 4 + r) sc[n][r] = -INFINITY;          \
    }                                                                            \
    float pm[4];                                                                 \
    _Pragma("unroll")                                                            \
    for (int r = 0; r < 4; ++r) {                                                \
      float tm = fmaxf(fmaxf(sc[0][r], sc[1][r]), fmaxf(sc[2][r], sc[3][r]));    \
      tm = fmaxf(tm, __shfl_xor(tm, 1));                                         \
      tm = fmaxf(tm, __shfl_xor(tm, 2));                                         \
      tm = fmaxf(tm, __shfl_xor(tm, 4));                                         \
      tm = fmaxf(tm, __shfl_xor(tm, 8));                                         \
      pm[r] = tm;                                                                 \
    }                                                                            \
    float growth = fmaxf(fmaxf(pm[0] - MM[0], pm[1] - MM[1]),                    \
                         fmaxf(pm[2] - MM[2], pm[3] - MM[3]));                   \
    if (!__all(growth <= 8.f)) {                                                 \
      _Pragma("unroll")                                                          \
      for (int r = 0; r < 4; ++r) {                                              \
        float mn = fmaxf(MM[r], pm[r]);                                          \
        float corr = __builtin_amdgcn_exp2f(MM[r] - mn);                         \
        MM[r] = mn;                                                              \
        OO[0][r] *= corr; OO[1][r] *= corr; OO[2][r] *= corr; OO[3][r] *= corr;  \
        LS[r] *= corr;                                                           \
      }                                                                          \
    }                                                                            \
    _Pragma("unroll")                                                            \
    for (int r = 0; r < 4; ++r) {                                                \
      const int pr = (w * 16 + l4 * 4 + r) * 72;                                 \
      _Pragma("unroll")                                                          \
      for (int n = 0; n < 4; ++n)                                                \
        Ps[pr + n * 16 + l15] = f2bf(__builtin_amdgcn_exp2f(sc[n][r] - MM[r]));  \
    }                                                                            \
    const int prow = (w * 16 + l15) * 72;                                        \
    __builtin_amdgcn_s_setprio(1);                                               \
    _Pragma("unroll")                                                            \
    for (int c = 0; c < 2; ++c) {                                                \
      s16x8 pa = *(const s16x8*)&Ps[prow + c * 32 + 8 * l4];                     \
      const int swz = ((c * 4 + l4) ^ l7) * 8;                                   \
      _Pragma("unroll")                                                          \
      for (int n = 0; n < 4; ++n) {                                              \
        s16x8 vb = *(const s16x8*)&Vs[CUR][(n * 16 + l15) * 64 + swz];           \
        OO[n] = __builtin_amdgcn_mfma_f32_16x16x32_bf16(pa, vb, OO[n], 0, 0, 0); \
      }                                                                          \
      LS = __builtin_amdgcn_mfma_f32_16x16x32_bf16(pa, ones, LS, 0, 0, 0);       \
    }                                                                            \
    __builtin_amdgcn_s_setprio(0);                                               \
  } while (0)

__global__ __launch_bounds__(256) void attn_mfma_kernel(
    const unsigned short* __restrict__ Qhi, const unsigned short* __restrict__ Qlo,
    const unsigned short* __restrict__ Khi_g, const unsigned short* __restrict__ Vt_g,
    unsigned short* __restrict__ Ohi) {
  __shared__ __align__(16) unsigned short Ks[2][64 * 64];
  __shared__ __align__(16) unsigned short Vs[2][64 * 64];
  __shared__ __align__(16) unsigned short Ps[64 * 72];

  const int t = threadIdx.x;
  const int lane = t & 63;
  const int w = t >> 6;
  // 1024 blocks: xcd = flat&7; within-XCD, qi descends first (long-first),
  // 4 heads per XCD for K/V L2 residency.
  const int flat = (int)blockIdx.y * 32 + (int)blockIdx.x;
  const int xcd = flat & 7, slot = flat >> 3;       // slot 0..127
  const int qi = 31 - (slot >> 2);                  // 31..0, long first
  const int bh = (xcd << 2) | (slot & 3);           // 0..31
  const int b = bh >> 4, h = bh & 15;
  const int l15 = lane & 15, l4 = lane >> 4, l7 = lane & 7;

  s16x8 qh[2], ql[2];
  {
    const int rowA = qi * 64 + w * 16 + l15;
    const unsigned short* qb = Qhi + ((size_t)bh * SS + rowA) * HDD + 8 * l4;
    const unsigned short* qc = Qlo + ((size_t)bh * SS + rowA) * HDD + 8 * l4;
    qh[0] = *(const s16x8*)(qb);
    qh[1] = *(const s16x8*)(qb + 32);
    ql[0] = *(const s16x8*)(qc);
    ql[1] = *(const s16x8*)(qc + 32);
  }

  // staging maps: linear LDS dest, inverse-swizzled global source (rule #21)
  int lds[2];
  size_t koff[2], voff[2];
#pragma unroll
  for (int c = 0; c < 2; ++c) {
    int G = t + c * 256;
    int row = G >> 3, g = G & 7;
    int gs = g ^ (row & 7);
    lds[c] = G * 8;
    koff[c] = ((size_t)bh * SS + row) * HDD + gs * 8;
    voff[c] = ((size_t)bh * HDD + row) * SS + gs * 8;
  }

  const f32x4 z = {0.f, 0.f, 0.f, 0.f};
  f32x4 o[4], ls = z;
#pragma unroll
  for (int n = 0; n < 4; ++n) o[n] = z;
  float m[4];
#pragma unroll
  for (int r = 0; r < 4; ++r) m[r] = -INFINITY;

  const short one_bf = (short)0x3F80;
  const s16x8 ones = {one_bf, one_bf, one_bf, one_bf, one_bf, one_bf, one_bf, one_bf};

  // prologue: stage tile 0 into buffer 0
#pragma unroll
  for (int c = 0; c < 2; ++c) {
    GLDS16(Khi_g + koff[c], &Ks[0][lds[c]]);
    GLDS16(Vt_g + voff[c], &Vs[0][lds[c]]);
  }
  __syncthreads();

  int cur = 0;
  for (int kt = 0; kt <= qi; ++kt) {
    if (kt < qi) {  // prefetch next tile (concurrent with compute)
      const size_t ka = (size_t)(kt + 1) * 64 * HDD;
      const size_t va = (size_t)(kt + 1) * 64;
      const int nxt = cur ^ 1;
#pragma unroll
      for (int c = 0; c < 2; ++c) {
        GLDS16(Khi_g + ka + koff[c], &Ks[nxt][lds[c]]);
        GLDS16(Vt_g + va + voff[c], &Vs[nxt][lds[c]]);
      }
    }
    ATTN_TILE(qh, ql, o, ls, m, kt == qi, cur);
    __syncthreads();  // drains prefetch vmcnt; protects buffer swap
    cur ^= 1;
  }

  // epilogue
#pragma unroll
  for (int r = 0; r < 4; ++r) {
    const float inv = 1.f / ls[r];
    const int orow = qi * 64 + w * 16 + l4 * 4 + r;
    const size_t ob = ((size_t)b * SS + orow) * DD + h * HDD + l15;
#pragma unroll
    for (int n = 0; n < 4; ++n)
      Ohi[ob + n * 16] = f2bf(o[n][r] * inv);
  }
}

extern "C" void kernel_launch(void* const* d_in, const int* in_sizes, int n_in,
                              void* d_out, int out_size, void* d_ws, size_t ws_size,
                              hipStream_t stream) {
  const float* query = (const float*)d_in[0];
  const float* sin_q = (const float*)d_in[1];
  const float* cos_q = (const float*)d_in[2];
  const float* sin_k = (const float*)d_in[3];
  const float* cos_k = (const float*)d_in[4];
  const float* w_in  = (const float*)d_in[5];
  const float* w_out = (const float*)d_in[6];
  float* out = (float*)d_out;

  const int M = BB * SS;  // 4096
  const size_t MD = (size_t)M * DD;

  unsigned char* ws = (unsigned char*)d_ws;
  size_t off = 0;
  unsigned short* Qb  = (unsigned short*)(ws + off); off += MD * 2;
  unsigned short* B1h = (unsigned short*)(ws + off); off += (size_t)DD * 3 * DD * 2;
  unsigned short* B2h = (unsigned short*)(ws + off); off += (size_t)DD * DD * 2;
  unsigned short* Qhi = (unsigned short*)(ws + off); off += MD * 2;
  unsigned short* Qlo = (unsigned short*)(ws + off); off += MD * 2;
  unsigned short* Khi = (unsigned short*)(ws + off); off += MD * 2;
  unsigned short* Vt  = (unsigned short*)(ws + off); off += MD * 2;
  unsigned short* Ohi = (unsigned short*)(ws + off); off += MD * 2;

  {  // pre-pass: A cast + weight transposes
    int n4 = (int)(MD / 4);
    cast_bf16_kernel<<<(n4 + 255) / 256, 256, 0, stream>>>(query, Qb, n4);
    cast_transpose_kernel<<<dim3(3 * DD / 64, DD / 64), 256, 0, stream>>>(w_in, B1h, DD, 3 * DD);
    cast_transpose_kernel<<<dim3(DD / 64, DD / 64), 256, 0, stream>>>(w_out, B2h, DD, DD);
  }
  {  // 1) fused QKV projection + RoPE + head-split + V-transpose (1-term)
    dim3 grid((3 * DD) / 128, M / 128);
    gemm_qkv_rope_kernel<<<grid, 256, 0, stream>>>(
        Qb, B1h, sin_q, cos_q, sin_k, cos_k, Qhi, Qlo, Khi, Vt);
  }
  {  // 2) causal attention (unpaired tiles, 1024 blocks, long-first)
    dim3 grid(32, 32);
    attn_mfma_kernel<<<grid, 256, 0, stream>>>(Qhi, Qlo, Khi, Vt, Ohi);
  }
  {  // 3) output projection (1-term)
    dim3 grid(DD / 128, M / 128);
    gemm_out_kernel<<<grid, 256, 0, stream>>>(Ohi, B2h, out);
  }
}